// Round 11
// baseline (461.554 us; speedup 1.0000x reference)
//
#include <hip/hip_runtime.h>

// Problem constants (fixed by the reference)
#define NB    2
#define LQT   12096      // query tokens per batch
#define LINT  2304       // feat tokens per batch (48*48)
#define DIMC  768
#define NHD   6
#define NPT   4
#define DHD   128
#define HIDC  192
#define HH    48
#define WW    48

typedef __attribute__((ext_vector_type(8))) short bf16x8;
typedef __attribute__((ext_vector_type(4))) float f32x4;

__device__ __forceinline__ unsigned short f2bf(float f) {
  unsigned int u = __builtin_bit_cast(unsigned int, f);
  u += 0x7FFFu + ((u >> 16) & 1u);   // round-to-nearest-even
  return (unsigned short)(u >> 16);
}
__device__ __forceinline__ float bf2f(unsigned short h) {
  unsigned int u = ((unsigned int)h) << 16;
  return __builtin_bit_cast(float, u);
}

// global -> LDS direct copy, 16B per lane. LDS dest = wave-uniform + lane*16.
__device__ __forceinline__ void gload16(const unsigned short* g, unsigned short* l) {
  __builtin_amdgcn_global_load_lds(
      (const __attribute__((address_space(1))) unsigned int*)g,
      (__attribute__((address_space(3))) unsigned int*)l, 16, 0, 0);
}

// ---------------- weight packing: transpose [K][N]->bf16 [rows>=N][K], pad rows with 0
__global__ __launch_bounds__(256) void pack_wt(const float* __restrict__ src,
                                               unsigned short* __restrict__ dst,
                                               int K, int N, int rows) {
  size_t i = (size_t)blockIdx.x * 256 + threadIdx.x;
  if (i >= (size_t)rows * K) return;
  int n = (int)(i / K), k = (int)(i % K);
  float v = (n < N) ? src[(size_t)k * N + n] : 0.f;
  dst[i] = f2bf(v);
}

// fused sampling-offset (48 cols) + attn-weight (24 cols) weight pack into [128][768]
__global__ __launch_bounds__(256) void pack_soaw(const float* __restrict__ soW,
                                                 const float* __restrict__ awW,
                                                 const float* __restrict__ sob,
                                                 const float* __restrict__ awb,
                                                 unsigned short* __restrict__ dst,
                                                 float* __restrict__ bdst) {
  size_t i = (size_t)blockIdx.x * 256 + threadIdx.x;
  if (i < 128) bdst[i] = (i < 48) ? sob[i] : (i < 72 ? awb[i - 48] : 0.f);
  if (i >= (size_t)128 * DIMC) return;
  int n = (int)(i / DIMC), k = (int)(i % DIMC);
  float v = (n < 48) ? soW[(size_t)k * 48 + n]
                     : (n < 72 ? awW[(size_t)k * 24 + (n - 48)] : 0.f);
  dst[i] = f2bf(v);
}

// ---------------- LayerNorm (eps=1e-6), fp32 in -> bf16 out
__global__ __launch_bounds__(256) void ln_to_bf16(const float* __restrict__ in,
                                                  const float* __restrict__ gamma,
                                                  const float* __restrict__ beta,
                                                  unsigned short* __restrict__ out) {
  const int row = blockIdx.x;
  const int t = threadIdx.x;
  const float* x = in + (size_t)row * DIMC;
  float v0 = x[t], v1 = x[t + 256], v2 = x[t + 512];
  float s = v0 + v1 + v2;
  float s2 = v0 * v0 + v1 * v1 + v2 * v2;
#pragma unroll
  for (int o = 32; o > 0; o >>= 1) {
    s += __shfl_down(s, o);
    s2 += __shfl_down(s2, o);
  }
  __shared__ float red[8];
  const int wave = t >> 6, lane = t & 63;
  if (lane == 0) { red[wave] = s; red[wave + 4] = s2; }
  __syncthreads();
  float S = red[0] + red[1] + red[2] + red[3];
  float S2 = red[4] + red[5] + red[6] + red[7];
  float mean = S * (1.0f / DIMC);
  float var = S2 * (1.0f / DIMC) - mean * mean;
  float inv = rsqrtf(var + 1e-6f);
  unsigned short* o0 = out + (size_t)row * DIMC;
  o0[t]       = f2bf((v0 - mean) * inv * gamma[t]       + beta[t]);
  o0[t + 256] = f2bf((v1 - mean) * inv * gamma[t + 256] + beta[t + 256]);
  o0[t + 512] = f2bf((v2 - mean) * inv * gamma[t + 512] + beta[t + 512]);
}

// ---------------- LDS-pipelined MFMA GEMM (R3-proven; v-proj, soaw, fc1)
// BK=64 double-buffer, 4 waves (2x2), 2-phase loop, slot^(row&7) XOR both sides.
template <int WM, int WN, bool OUT_BF16>
__global__ __launch_bounds__(256) void gemm_bt(const unsigned short* __restrict__ A,
                                               const unsigned short* __restrict__ Bt,
                                               const float* __restrict__ bias,
                                               void* __restrict__ out_,
                                               int M, int N, int K, int nn) {
  constexpr int BM = 2 * WM * 16;
  constexpr int BN = 2 * WN * 16;
  constexpr int CHA = BM * 8;
  constexpr int CHT = (BM + BN) * 8;
  __shared__ unsigned short As[2][BM * 64];
  __shared__ unsigned short Bs[2][BN * 64];
  const int t = threadIdx.x;
  const int wave = t >> 6, lane = t & 63;

  const int nwg = gridDim.x;
  const int qq = nwg >> 3, rr = nwg & 7;
  const int xcd = blockIdx.x & 7, pos = blockIdx.x >> 3;
  const int swz = ((xcd < rr) ? xcd * (qq + 1) : rr * (qq + 1) + (xcd - rr) * qq) + pos;
  const int m0 = (swz / nn) * BM;
  const int n0 = (swz % nn) * BN;

  const int wm = (wave >> 1) * (WM * 16), wn = (wave & 1) * (WN * 16);
  const int lr = lane & 15;
  const int lg = lane >> 4;

  auto stage = [&](int buf, int k0) {
#pragma unroll
    for (int i = 0; i < CHT / 256; ++i) {
      const int c = t + i * 256;
      if (c < CHA) {
        const int row = c >> 3, slot = c & 7;
        const int ca = slot ^ (row & 7);
        gload16(A + (size_t)(m0 + row) * K + k0 + ca * 8, &As[buf][c * 8]);
      } else {
        const int c2 = c - CHA, row = c2 >> 3, slot = c2 & 7;
        const int ca = slot ^ (row & 7);
        gload16(Bt + (size_t)(n0 + row) * K + k0 + ca * 8, &Bs[buf][c2 * 8]);
      }
    }
  };

  f32x4 acc[WM][WN] = {};

  stage(0, 0);
  __syncthreads();
  int cur = 0;

  for (int k0 = 0; k0 < K; k0 += 64) {
    if (k0 + 64 < K) stage(cur ^ 1, k0 + 64);

    bf16x8 af[2][WM], bg[2][WN];
#pragma unroll
    for (int kk = 0; kk < 2; ++kk) {
#pragma unroll
      for (int i = 0; i < WM; ++i) {
        const int row = wm + i * 16 + lr;
        const int slot = (kk * 4 + lg) ^ (row & 7);
        af[kk][i] = *(const bf16x8*)(&As[cur][row * 64 + slot * 8]);
      }
#pragma unroll
      for (int j = 0; j < WN; ++j) {
        const int row = wn + j * 16 + lr;
        const int slot = (kk * 4 + lg) ^ (row & 7);
        bg[kk][j] = *(const bf16x8*)(&Bs[cur][row * 64 + slot * 8]);
      }
    }
#pragma unroll
    for (int kk = 0; kk < 2; ++kk)
#pragma unroll
      for (int i = 0; i < WM; ++i)
#pragma unroll
        for (int j = 0; j < WN; ++j)
          acc[i][j] = __builtin_amdgcn_mfma_f32_16x16x32_bf16(af[kk][i], bg[kk][j], acc[i][j], 0, 0, 0);

    __syncthreads();
    cur ^= 1;
  }

  const int orow = lg * 4;
  float* outf = (float*)out_;
  unsigned short* outb = (unsigned short*)out_;
#pragma unroll
  for (int i = 0; i < WM; ++i) {
#pragma unroll
    for (int j = 0; j < WN; ++j) {
      const int n = n0 + wn + j * 16 + lr;
      if (n < N) {
#pragma unroll
        for (int r = 0; r < 4; ++r) {
          const int m = m0 + wm + i * 16 + orow + r;
          if (m < M) {
            float v = acc[i][j][r] + bias[n];
            if (OUT_BF16) outb[(size_t)m * N + n] = f2bf(v);
            else          outf[(size_t)m * N + n] = v;
          }
        }
      }
    }
  }
}

// ---------------- 256x256 deep-pipelined MFMA GEMM (out-proj, fc2).
// BK=32, 8 waves (2M x 4N), wave-tile 128x64 (32 MFMA/K-step). QUAD-buffered
// LDS (4 x 32KB = 128KB) -> 2 tiles always in flight via counted vmcnt (T3+T4):
// per K-step: vmcnt(8) [tile k landed, k+1/k+2 flying] -> ONE s_barrier ->
// stage tile k+3 into buf[(k+3)&3] -> plain-C++ ds_reads (compiler emits
// counted lgkmcnt) -> setprio-wrapped MFMA. No mid-loop vmcnt(0).
// Overwrite safety: buf[(k+3)&3]'s last reads (step k-1) retired before any
// wave passes barrier k (compiler waits ds_reads before their MFMA uses).
// XOR slot^((row>>1)&3) on BOTH stage source and ds_read (R4-measured 0-conflict).
// out = acc + bias + add (fp32), always. K%32==0, NT>=3. N multiple of 256.
__global__ __launch_bounds__(512, 2) void gemm256(const unsigned short* __restrict__ A,
                                                  const unsigned short* __restrict__ Bt,
                                                  const float* __restrict__ bias,
                                                  const float* __restrict__ add,
                                                  float* __restrict__ out,
                                                  int M, int N, int K, int nn) {
  __shared__ unsigned short As[4][256 * 32];
  __shared__ unsigned short Bs[4][256 * 32];
  const int t = threadIdx.x;
  const int wave = t >> 6, lane = t & 63;
  const int lr = lane & 15, lg = lane >> 4;

  const int nwg = gridDim.x;
  const int qq = nwg >> 3, rr = nwg & 7;
  const int xcd = blockIdx.x & 7, pos = blockIdx.x >> 3;
  const int swz = ((xcd < rr) ? xcd * (qq + 1) : rr * (qq + 1) + (xcd - rr) * qq) + pos;
  const int m0 = (swz / nn) * 256;
  const int n0 = (swz % nn) * 256;

  const int wm = (wave >> 2) * 128;   // 2 m-halves
  const int wn = (wave & 3) * 64;     // 4 n-quarters

  // stage one K-tile (A 16KB + B 16KB): 1024 chunks each side, 2/thread/side
  auto stage = [&](int buf, int kt) {
    const int k0 = kt * 32;
#pragma unroll
    for (int i = 0; i < 2; ++i) {
      const int c = t + i * 512;
      const int row = c >> 2, slot = c & 3;
      const int ca = slot ^ ((row >> 1) & 3);
      gload16(A + (size_t)(m0 + row) * K + k0 + ca * 8, &As[buf][c * 8]);
    }
#pragma unroll
    for (int i = 0; i < 2; ++i) {
      const int c = t + i * 512;
      const int row = c >> 2, slot = c & 3;
      const int ca = slot ^ ((row >> 1) & 3);
      gload16(Bt + (size_t)(n0 + row) * K + k0 + ca * 8, &Bs[buf][c * 8]);
    }
  };

  f32x4 acc[8][4] = {};
  const int NT = K >> 5;     // >= 3 required

  stage(0, 0);               // 4 VMEM instrs per stage (per wave)
  stage(1, 1);
  stage(2, 2);

  for (int kt = 0; kt < NT; ++kt) {
    if (kt < NT - 2)       asm volatile("s_waitcnt vmcnt(8)" ::: "memory");
    else if (kt == NT - 2) asm volatile("s_waitcnt vmcnt(4)" ::: "memory");
    else                   asm volatile("s_waitcnt vmcnt(0)" ::: "memory");
    __builtin_amdgcn_s_barrier();      // tile kt visible to all waves
    asm volatile("" ::: "memory");     // no ds_read hoist above barrier

    if (kt + 3 < NT) stage((kt + 3) & 3, kt + 3);   // 2 tiles stay in flight

    const unsigned short* asb = &As[kt & 3][0];
    const unsigned short* bsb = &Bs[kt & 3][0];
    bf16x8 bg[4];
#pragma unroll
    for (int j = 0; j < 4; ++j) {
      const int row = wn + j * 16 + lr;
      const int slot = lg ^ ((row >> 1) & 3);
      bg[j] = *(const bf16x8*)(&bsb[row * 32 + slot * 8]);
    }
    __builtin_amdgcn_s_setprio(1);
#pragma unroll
    for (int mf = 0; mf < 8; ++mf) {
      const int row = wm + mf * 16 + lr;
      const int slot = lg ^ ((row >> 1) & 3);
      const bf16x8 af = *(const bf16x8*)(&asb[row * 32 + slot * 8]);
#pragma unroll
      for (int j = 0; j < 4; ++j)
        acc[mf][j] = __builtin_amdgcn_mfma_f32_16x16x32_bf16(af, bg[j], acc[mf][j], 0, 0, 0);
    }
    __builtin_amdgcn_s_setprio(0);
  }

#pragma unroll
  for (int mf = 0; mf < 8; ++mf) {
#pragma unroll
    for (int j = 0; j < 4; ++j) {
      const int n = n0 + wn + j * 16 + lr;
#pragma unroll
      for (int r = 0; r < 4; ++r) {
        const int m = m0 + wm + mf * 16 + lg * 4 + r;
        if (m < M)
          out[(size_t)m * N + n] = acc[mf][j][r] + bias[n] + add[(size_t)m * N + n];
      }
    }
  }
}

// ---------------- deformable sampling: softmax(attw) + bilinear gather + NP-sum
__global__ __launch_bounds__(192) void deform_attn(const float* __restrict__ soaw,
                                                   const float* __restrict__ rp,
                                                   const float* __restrict__ value,
                                                   unsigned short* __restrict__ attn) {
  const int row = blockIdx.x;  // b*LQT + q
  const int b = row / LQT;
  const int t = threadIdx.x;
  const int h = t >> 5;
  const int l = t & 31;
  const float* sa = soaw + (size_t)row * 128;
  const float bx = rp[(size_t)row * 2 + 0] * (float)WW - 0.5f;
  const float by = rp[(size_t)row * 2 + 1] * (float)HH - 0.5f;

  float lg0 = sa[48 + h * 4 + 0], lg1 = sa[48 + h * 4 + 1];
  float lg2 = sa[48 + h * 4 + 2], lg3 = sa[48 + h * 4 + 3];
  float mx = fmaxf(fmaxf(lg0, lg1), fmaxf(lg2, lg3));
  float e0 = expf(lg0 - mx), e1 = expf(lg1 - mx), e2 = expf(lg2 - mx), e3 = expf(lg3 - mx);
  float inv = 1.0f / (e0 + e1 + e2 + e3);
  float awp[4] = {e0 * inv, e1 * inv, e2 * inv, e3 * inv};

  const float* vb = value + (size_t)b * LINT * DIMC + h * DHD + l * 4;
  float ax = 0.f, ay = 0.f, az = 0.f, aw = 0.f;
#pragma unroll
  for (int p = 0; p < 4; ++p) {
    float fx = bx + sa[h * 8 + p * 2 + 0];
    float fy = by + sa[h * 8 + p * 2 + 1];
    float x0f = floorf(fx), y0f = floorf(fy);
    float wx = fx - x0f, wy = fy - y0f;
    int x0 = (int)x0f, y0 = (int)y0f;
#pragma unroll
    for (int dy = 0; dy < 2; ++dy) {
#pragma unroll
      for (int dx = 0; dx < 2; ++dx) {
        int xi = x0 + dx, yi = y0 + dy;
        float w = (dy ? wy : 1.f - wy) * (dx ? wx : 1.f - wx) * awp[p];
        if (xi < 0 || xi >= WW || yi < 0 || yi >= HH) w = 0.f;
        int xc = min(max(xi, 0), WW - 1), yc = min(max(yi, 0), HH - 1);
        const float4 g = *(const float4*)(vb + (size_t)(yc * WW + xc) * DIMC);
        ax += w * g.x; ay += w * g.y; az += w * g.z; aw += w * g.w;
      }
    }
  }
  unsigned short* op = attn + (size_t)row * DIMC + h * DHD + l * 4;
  ushort4 ov;
  ov.x = f2bf(ax); ov.y = f2bf(ay); ov.z = f2bf(az); ov.w = f2bf(aw);
  *(ushort4*)op = ov;
}

// ---------------- depthwise 3x3 conv (3 image scales) + exact GELU, bf16 in/out
__global__ __launch_bounds__(192) void dwconv_gelu(const unsigned short* __restrict__ h1,
                                                   const float* __restrict__ dwW,
                                                   const float* __restrict__ dwb,
                                                   unsigned short* __restrict__ out) {
  const int blk = blockIdx.x;  // b*LQT + q
  const int b = blk / LQT;
  const int q = blk % LQT;
  int base, Wi, Hi;
  if (q < 9216)       { base = 0;     Wi = 96; Hi = 96; }
  else if (q < 11520) { base = 9216;  Wi = 48; Hi = 48; }
  else                { base = 11520; Wi = 24; Hi = 24; }
  const int loc = q - base;
  const int y = loc / Wi, x = loc % Wi;
  const int c = threadIdx.x;
  const unsigned short* src = h1 + ((size_t)b * LQT + base) * HIDC + c;
  float acc = dwb[c];
#pragma unroll
  for (int dy = -1; dy <= 1; ++dy) {
    int yy = y + dy;
    if (yy < 0 || yy >= Hi) continue;
#pragma unroll
    for (int dx = -1; dx <= 1; ++dx) {
      int xx = x + dx;
      if (xx < 0 || xx >= Wi) continue;
      acc += dwW[c * 9 + (dy + 1) * 3 + (dx + 1)] * bf2f(src[(size_t)(yy * Wi + xx) * HIDC]);
    }
  }
  float g = 0.5f * acc * (1.0f + erff(acc * 0.70710678118654752f));
  out[(size_t)blk * HIDC + c] = f2bf(g);
}

// ---------------- launch
extern "C" void kernel_launch(void* const* d_in, const int* in_sizes, int n_in,
                              void* d_out, int out_size, void* d_ws, size_t ws_size,
                              hipStream_t stream) {
  const float* query = (const float*)d_in[0];
  const float* rp    = (const float*)d_in[1];
  const float* feat  = (const float*)d_in[2];
  const float* qn_g  = (const float*)d_in[7];
  const float* qn_b  = (const float*)d_in[8];
  const float* fn_g  = (const float*)d_in[9];
  const float* fn_b  = (const float*)d_in[10];
  const float* mn_g  = (const float*)d_in[11];
  const float* mn_b  = (const float*)d_in[12];
  const float* vW    = (const float*)d_in[13];
  const float* vb    = (const float*)d_in[14];
  const float* soW   = (const float*)d_in[15];
  const float* sob   = (const float*)d_in[16];
  const float* awW   = (const float*)d_in[17];
  const float* awb   = (const float*)d_in[18];
  const float* opW   = (const float*)d_in[19];
  const float* opb   = (const float*)d_in[20];
  const float* fc1W  = (const float*)d_in[21];
  const float* fc1b  = (const float*)d_in[22];
  const float* dwW   = (const float*)d_in[23];
  const float* dwb   = (const float*)d_in[24];
  const float* fc2W  = (const float*)d_in[25];
  const float* fc2b  = (const float*)d_in[26];
  float* out = (float*)d_out;
  (void)in_sizes; (void)n_in; (void)out_size; (void)ws_size;

  char* ws = (char*)d_ws;
  size_t off = 0;
  auto alloc = [&](size_t bytes) -> void* {
    off = (off + 255) & ~(size_t)255;
    void* p = ws + off;
    off += bytes;
    return p;
  };

  const int MQ = NB * LQT;    // 24192 = 189*128
  const int MQP = 24320;      // MQ rounded up to 256 (pad rows for BM=256 staging)
  const int MF = NB * LINT;   // 4608 = 36*128

  unsigned short* vWt    = (unsigned short*)alloc((size_t)768 * 768 * 2);
  unsigned short* opWt   = (unsigned short*)alloc((size_t)768 * 768 * 2);
  unsigned short* soawWt = (unsigned short*)alloc((size_t)128 * 768 * 2);
  unsigned short* fc1Wt  = (unsigned short*)alloc((size_t)192 * 768 * 2);
  unsigned short* fc2Wt  = (unsigned short*)alloc((size_t)768 * 192 * 2);
  float*          soawb  = (float*)alloc(128 * 4);
  unsigned short* f_ln   = (unsigned short*)alloc((size_t)MF * DIMC * 2);
  unsigned short* q_ln   = (unsigned short*)alloc((size_t)MQ * DIMC * 2);  // reused as ln(x)
  float*          value  = (float*)alloc((size_t)MF * DIMC * 4);
  float*          soaw   = (float*)alloc((size_t)MQP * 128 * 4);           // reused as conv out (bf16, padded)
  unsigned short* attnb  = (unsigned short*)alloc((size_t)MQP * DIMC * 2); // padded rows; reused as h1 (bf16)
  float*          xbuf   = (float*)alloc((size_t)MQ * DIMC * 4);           // x residual (fp32)

  unsigned short* h1b = attnb;                   // fc1 output (bf16), after attnb consumed
  unsigned short* coutb = (unsigned short*)soaw; // MQP*192*2 = 9.3MB < 12.4MB
  unsigned short* lnx = q_ln;

  // weight packing (tiny)
  pack_wt<<<dim3((768 * 768 + 255) / 256), dim3(256), 0, stream>>>(vW, vWt, 768, 768, 768);
  pack_wt<<<dim3((768 * 768 + 255) / 256), dim3(256), 0, stream>>>(opW, opWt, 768, 768, 768);
  pack_wt<<<dim3((192 * 768 + 255) / 256), dim3(256), 0, stream>>>(fc1W, fc1Wt, 768, 192, 192);
  pack_wt<<<dim3((768 * 192 + 255) / 256), dim3(256), 0, stream>>>(fc2W, fc2Wt, 192, 768, 768);
  pack_soaw<<<dim3((128 * 768 + 255) / 256), dim3(256), 0, stream>>>(soW, awW, sob, awb, soawWt, soawb);

  // LayerNorms (fp32 in)
  ln_to_bf16<<<dim3(MF), dim3(256), 0, stream>>>(feat, fn_g, fn_b, f_ln);
  ln_to_bf16<<<dim3(MQ), dim3(256), 0, stream>>>(query, qn_g, qn_b, q_ln);

  // value projection: [4608,768] = f_ln @ vW + vb   (BM=64, grid 72x6)
  gemm_bt<2, 4, false><<<dim3((MF / 64) * 6), dim3(256), 0, stream>>>(
      f_ln, vWt, vb, value, MF, 768, 768, 6);

  // sampling offsets + attn logits (N=128 padded; BM=64, grid 378)
  gemm_bt<2, 4, false><<<dim3(MQ / 64), dim3(256), 0, stream>>>(
      q_ln, soawWt, soawb, soaw, MQ, 128, 768, 1);

  // deformable bilinear sampling -> attn operand (bf16)
  deform_attn<<<dim3(MQ), dim3(192), 0, stream>>>(soaw, rp, value, attnb);

  // output projection + residual: x = attn @ opW + opb + query (256x256 pipeline, fp32 out)
  gemm256<<<dim3((MQP / 256) * 3), dim3(512), 0, stream>>>(
      attnb, opWt, opb, query, xbuf, MQ, 768, 768, 3);

  // LN(x)
  ln_to_bf16<<<dim3(MQ), dim3(256), 0, stream>>>(xbuf, mn_g, mn_b, lnx);

  // fc1: h1 = lnx @ fc1W + fc1b  (BM=128, BN=64, grid 189x3, bf16 out)
  gemm_bt<4, 2, true><<<dim3((MQ / 128) * 3), dim3(256), 0, stream>>>(
      lnx, fc1Wt, fc1b, h1b, MQ, 192, 768, 3);

  // depthwise conv (3 scales) + GELU (bf16 in/out)
  dwconv_gelu<<<dim3(MQ), dim3(192), 0, stream>>>(h1b, dwW, dwb, coutb);

  // fc2 + residual: out = x + cout @ fc2W + fc2b (256x256 pipeline, K=192, NT=6)
  gemm256<<<dim3((MQP / 256) * 3), dim3(512), 0, stream>>>(
      coutb, fc2Wt, fc2b, xbuf, out, MQ, 768, 192, 3);
}